// Round 1
// baseline (10580.631 us; speedup 1.0000x reference)
//
#include <hip/hip_runtime.h>
#include <math.h>

#define N_ENT 10000
#define NROWPAD 10048   // 157*64, padded row length for snT/mnT
#define NTILES 157      // ceil(10000/64) column tiles
#define CSPLIT 4
#define INV_TAU 10.0f

__device__ __forceinline__ bool better(float v, int i, float bv, int bi) {
    return (v > bv) || (v == bv && i < bi);
}

__device__ __forceinline__ float sel6f(const float (&a)[6], int k) {
    return k == 0 ? a[0] : k == 1 ? a[1] : k == 2 ? a[2] : k == 3 ? a[3] : k == 4 ? a[4] : a[5];
}
__device__ __forceinline__ int sel6i(const int (&a)[6], int k) {
    return k == 0 ? a[0] : k == 1 ? a[1] : k == 2 ? a[2] : k == 3 ? a[3] : k == 4 ? a[4] : a[5];
}

// Static (register-only) sorted-desc top-6 insert. Lists stay sorted by better().
__device__ __forceinline__ void topk_insert(float (&v)[6], int (&ix)[6], float nv, int ni) {
    if (!better(nv, ni, v[5], ix[5])) return;
    bool b0 = better(v[0], ix[0], nv, ni);
    bool b1 = better(v[1], ix[1], nv, ni);
    bool b2 = better(v[2], ix[2], nv, ni);
    bool b3 = better(v[3], ix[3], nv, ni);
    bool b4 = better(v[4], ix[4], nv, ni);
    float o0 = v[0], o1 = v[1], o2 = v[2], o3 = v[3], o4 = v[4];
    int j0 = ix[0], j1 = ix[1], j2 = ix[2], j3 = ix[3], j4 = ix[4];
    v[0] = b0 ? o0 : nv;              ix[0] = b0 ? j0 : ni;
    v[1] = b1 ? o1 : (b0 ? nv : o0);  ix[1] = b1 ? j1 : (b0 ? ni : j0);
    v[2] = b2 ? o2 : (b1 ? nv : o1);  ix[2] = b2 ? j2 : (b1 ? ni : j1);
    v[3] = b3 ? o3 : (b2 ? nv : o2);  ix[3] = b3 ? j3 : (b2 ? ni : j2);
    v[4] = b4 ? o4 : (b3 ? nv : o3);  ix[4] = b4 ? j4 : (b3 ? ni : j3);
    v[5] = b4 ? nv : o4;              ix[5] = b4 ? ni : j4;
}

// ---------------- encoder GEMM (C = act(A @ B^T + bias)) ----------------
// A: [M][K] (optionally per-e via Astride), B: per-e [256][K], C: per-e [M][256]
template <bool GELU>
__global__ __launch_bounds__(256) void enc_gemm(const float* __restrict__ A, size_t Astride,
                                                const float* __restrict__ B,
                                                const float* __restrict__ bias,
                                                float* __restrict__ C, int M, int K) {
    const int e = blockIdx.z;
    const float* Ae = A + (size_t)e * Astride;
    const float* Be = B + (size_t)e * 256 * K;
    const float* be = bias + e * 256;
    float* Ce = C + (size_t)e * (size_t)M * 256;
    const int n0 = blockIdx.x * 64;
    const int o0 = blockIdx.y * 64;
    __shared__ float As[16][64];
    __shared__ float Bs[16][64];
    const int tid = threadIdx.x;
    const int tx = tid & 15, ty = tid >> 4;
    const int li = tid >> 2;
    const int lk = (tid & 3) * 4;
    float acc[4][4];
#pragma unroll
    for (int i = 0; i < 4; i++)
#pragma unroll
        for (int j = 0; j < 4; j++) acc[i][j] = 0.f;
    for (int kc = 0; kc < K; kc += 16) {
        float4 av = make_float4(0.f, 0.f, 0.f, 0.f);
        if (n0 + li < M) av = *(const float4*)(Ae + (size_t)(n0 + li) * K + kc + lk);
        As[lk + 0][li] = av.x; As[lk + 1][li] = av.y; As[lk + 2][li] = av.z; As[lk + 3][li] = av.w;
        float4 bv = *(const float4*)(Be + (size_t)(o0 + li) * K + kc + lk);
        Bs[lk + 0][li] = bv.x; Bs[lk + 1][li] = bv.y; Bs[lk + 2][li] = bv.z; Bs[lk + 3][li] = bv.w;
        __syncthreads();
#pragma unroll
        for (int k = 0; k < 16; k++) {
            float4 a4 = *(const float4*)&As[k][ty * 4];
            float4 b4 = *(const float4*)&Bs[k][tx * 4];
            float a[4] = {a4.x, a4.y, a4.z, a4.w}, b[4] = {b4.x, b4.y, b4.z, b4.w};
#pragma unroll
            for (int i = 0; i < 4; i++)
#pragma unroll
                for (int j = 0; j < 4; j++) acc[i][j] = fmaf(a[i], b[j], acc[i][j]);
        }
        __syncthreads();
    }
#pragma unroll
    for (int i = 0; i < 4; i++) {
        int gr = n0 + ty * 4 + i;
        if (gr >= M) continue;
#pragma unroll
        for (int j = 0; j < 4; j++) {
            int go = o0 + tx * 4 + j;
            float v = acc[i][j] + be[go];
            if (GELU) v = 0.5f * v * (1.0f + erff(v * 0.70710678118654752f));
            Ce[(size_t)gr * 256 + go] = v;
        }
    }
}

// ---------------- BatchNorm (training-mode batch stats, biased var) ----------------
__global__ __launch_bounds__(256) void bn_stats(const float* __restrict__ E,
                                                const float* __restrict__ gamma,
                                                const float* __restrict__ beta,
                                                float* __restrict__ bn_a, float* __restrict__ bn_b) {
    const int ch = blockIdx.x;  // e*256+o
    const int e = ch >> 8, o = ch & 255;
    const float* p = E + (size_t)e * N_ENT * 256 + o;
    float s = 0.f, ss = 0.f;
    for (int n = threadIdx.x; n < N_ENT; n += 256) {
        float v = p[(size_t)n * 256];
        s += v; ss += v * v;
    }
    __shared__ float sh1[4], sh2[4];
    int lane = threadIdx.x & 63, w = threadIdx.x >> 6;
    for (int off = 32; off; off >>= 1) { s += __shfl_down(s, off); ss += __shfl_down(ss, off); }
    if (lane == 0) { sh1[w] = s; sh2[w] = ss; }
    __syncthreads();
    if (threadIdx.x == 0) {
        s = sh1[0] + sh1[1] + sh1[2] + sh1[3];
        ss = sh2[0] + sh2[1] + sh2[2] + sh2[3];
        float mu = s * (1.f / N_ENT);
        float var = ss * (1.f / N_ENT) - mu * mu;
        float r = rsqrtf(var + 1e-5f);
        float a = gamma[ch] * r;
        bn_a[ch] = a;
        bn_b[ch] = beta[ch] - mu * a;
    }
}

__global__ __launch_bounds__(256) void bn_apply(float* __restrict__ E,
                                                const float* __restrict__ bn_a,
                                                const float* __restrict__ bn_b,
                                                float* __restrict__ out) {
    size_t idx = (size_t)blockIdx.x * 256 + threadIdx.x;
    int e = (int)(idx / ((size_t)N_ENT * 256));
    size_t rem = idx - (size_t)e * N_ENT * 256;
    int n = (int)(rem >> 8), o = (int)(rem & 255);
    int ch = (e << 8) | o;
    float v = E[idx] * bn_a[ch] + bn_b[ch];
    E[idx] = v;
    out[(size_t)n * 1280 + o * 5 + e] = v;  // mm_out: [N][256][5]
}

// ---------------- per-comp prep ----------------
__global__ __launch_bounds__(256) void rownorm(const float* __restrict__ base, size_t rowstride,
                                               int elemstride, float* __restrict__ rn) {
    int n = blockIdx.x;
    float v = base[(size_t)n * rowstride + (size_t)threadIdx.x * elemstride];
    float s = v * v;
    __shared__ float sh[4];
    int lane = threadIdx.x & 63, w = threadIdx.x >> 6;
    for (int off = 32; off; off >>= 1) s += __shfl_down(s, off);
    if (lane == 0) sh[w] = s;
    __syncthreads();
    if (threadIdx.x == 0) {
        s = sh[0] + sh[1] + sh[2] + sh[3];
        rn[n] = 1.f / (sqrtf(s) + 1e-12f);
    }
}

__global__ void build_snT(const float* __restrict__ st, int c, const float* __restrict__ rns,
                          float* __restrict__ snT) {
    __shared__ float t[32][33];
    int d0 = blockIdx.x * 32, n0 = blockIdx.y * 32;
    int tx = threadIdx.x, ty = threadIdx.y;
    int n = n0 + ty, d = d0 + tx;
    float v = 0.f;
    if (n < N_ENT) v = st[(size_t)n * 1280 + d * 5 + c];
    t[ty][tx] = v;
    __syncthreads();
    int nn = n0 + tx, dd = d0 + ty;
    if (nn < N_ENT) snT[(size_t)dd * NROWPAD + nn] = t[tx][ty] * rns[nn];
}

__global__ void build_mn(const float* __restrict__ E, int c, const float* __restrict__ rnm,
                         float* __restrict__ mn, float* __restrict__ mnT) {
    __shared__ float t[32][33];
    int o0 = blockIdx.x * 32, n0 = blockIdx.y * 32;
    int tx = threadIdx.x, ty = threadIdx.y;
    int n = n0 + ty, o = o0 + tx;
    float v = 0.f;
    if (n < N_ENT) {
        v = E[((size_t)c * N_ENT + n) * 256 + o] * rnm[n];
        mn[(size_t)n * 256 + o] = v;
    }
    t[ty][tx] = v;
    __syncthreads();
    int nn = n0 + tx, oo = o0 + ty;
    if (nn < N_ENT) mnT[(size_t)oo * NROWPAD + nn] = t[tx][ty];
}

// ---------------- pass 1: per-row argmax + sum(exp(cos/tau)) ----------------
__global__ __launch_bounds__(256) void pass1(const float* __restrict__ snT,
                                             const float* __restrict__ mnT,
                                             float* __restrict__ pmax, int* __restrict__ pidx,
                                             float* __restrict__ psum) {
    __shared__ float As[32][64];
    __shared__ float Bs[32][64];
    const int n0 = blockIdx.x * 64;
    const int cs = blockIdx.y;
    const int tid = threadIdx.x;
    const int tx = tid & 15, ty = tid >> 4;
    const int sk = tid >> 4;
    const int sj = (tid & 15) * 4;
    float maxv[4] = {-1e30f, -1e30f, -1e30f, -1e30f};
    int maxi[4] = {0, 0, 0, 0};
    float sume[4] = {0.f, 0.f, 0.f, 0.f};
    for (int ct = cs; ct < NTILES; ct += CSPLIT) {
        const int j0 = ct * 64;
        float acc[4][4];
#pragma unroll
        for (int i = 0; i < 4; i++)
#pragma unroll
            for (int j = 0; j < 4; j++) acc[i][j] = 0.f;
        for (int kc = 0; kc < 256; kc += 32) {
            *(float4*)&As[sk][sj]      = *(const float4*)(snT + (size_t)(kc + sk) * NROWPAD + n0 + sj);
            *(float4*)&As[sk + 16][sj] = *(const float4*)(snT + (size_t)(kc + sk + 16) * NROWPAD + n0 + sj);
            *(float4*)&Bs[sk][sj]      = *(const float4*)(mnT + (size_t)(kc + sk) * NROWPAD + j0 + sj);
            *(float4*)&Bs[sk + 16][sj] = *(const float4*)(mnT + (size_t)(kc + sk + 16) * NROWPAD + j0 + sj);
            __syncthreads();
#pragma unroll
            for (int k = 0; k < 32; k++) {
                float4 a4 = *(const float4*)&As[k][ty * 4];
                float4 b4 = *(const float4*)&Bs[k][tx * 4];
                float a[4] = {a4.x, a4.y, a4.z, a4.w}, b[4] = {b4.x, b4.y, b4.z, b4.w};
#pragma unroll
                for (int i = 0; i < 4; i++)
#pragma unroll
                    for (int j = 0; j < 4; j++) acc[i][j] = fmaf(a[i], b[j], acc[i][j]);
            }
            __syncthreads();
        }
#pragma unroll
        for (int j = 0; j < 4; j++) {
            int col = j0 + tx * 4 + j;
            if (col < N_ENT) {
#pragma unroll
                for (int i = 0; i < 4; i++) {
                    float v = acc[i][j];
                    sume[i] += __expf(v * INV_TAU);
                    if (v > maxv[i]) { maxv[i] = v; maxi[i] = col; }
                }
            }
        }
    }
    // butterfly across the 16 column-owning lanes (same wave)
#pragma unroll
    for (int m = 1; m < 16; m <<= 1) {
#pragma unroll
        for (int i = 0; i < 4; i++) {
            float ov = __shfl_xor(maxv[i], m);
            int oi = __shfl_xor(maxi[i], m);
            float os = __shfl_xor(sume[i], m);
            sume[i] += os;
            if (ov > maxv[i] || (ov == maxv[i] && oi < maxi[i])) { maxv[i] = ov; maxi[i] = oi; }
        }
    }
    if (tx == 0) {
#pragma unroll
        for (int i = 0; i < 4; i++) {
            int gr = n0 + ty * 4 + i;
            if (gr < N_ENT) {
                pmax[(size_t)cs * N_ENT + gr] = maxv[i];
                pidx[(size_t)cs * N_ENT + gr] = maxi[i];
                psum[(size_t)cs * N_ENT + gr] = sume[i];
            }
        }
    }
}

__global__ __launch_bounds__(256) void p1_combine(const float* __restrict__ pmax,
                                                  const int* __restrict__ pidx,
                                                  const float* __restrict__ psum,
                                                  int* __restrict__ amax, float* __restrict__ denom) {
    int n = blockIdx.x * 256 + threadIdx.x;
    if (n >= N_ENT) return;
    float bm = -1e30f; int bi = 0x7fffffff; float s = 0.f;
    for (int cs = 0; cs < CSPLIT; cs++) {
        float v = pmax[(size_t)cs * N_ENT + n];
        int ii = pidx[(size_t)cs * N_ENT + n];
        s += psum[(size_t)cs * N_ENT + n];
        if (v > bm || (v == bm && ii < bi)) { bm = v; bi = ii; }
    }
    amax[n] = bi;
    denom[n] = s;
}

// ---------------- pass 2: rows = mn[amax] @ mn^T, streaming top-6 ----------------
__global__ __launch_bounds__(256) void pass2(const float* __restrict__ mn,
                                             const float* __restrict__ mnT,
                                             const int* __restrict__ amax,
                                             float* __restrict__ tval, int* __restrict__ tidx) {
    __shared__ float As[32][64];
    __shared__ float Bs[32][64];
    __shared__ int rowsel[64];
    const int n0 = blockIdx.x * 64;
    const int cs = blockIdx.y;
    const int tid = threadIdx.x;
    const int tx = tid & 15, ty = tid >> 4;
    if (tid < 64) {
        int g = n0 + tid;
        rowsel[tid] = (g < N_ENT) ? amax[g] : 0;
    }
    __syncthreads();
    const int si = tid >> 2;
    const int skq = (tid & 3) * 4;
    const int sk = tid >> 4;
    const int sj = (tid & 15) * 4;
    float tv[4][6]; int ti[4][6];
#pragma unroll
    for (int i = 0; i < 4; i++)
#pragma unroll
        for (int s = 0; s < 6; s++) { tv[i][s] = -1e30f; ti[i][s] = 0x7fffffff; }
    for (int ct = cs; ct < NTILES; ct += CSPLIT) {
        const int j0 = ct * 64;
        float acc[4][4];
#pragma unroll
        for (int i = 0; i < 4; i++)
#pragma unroll
            for (int j = 0; j < 4; j++) acc[i][j] = 0.f;
        for (int kc = 0; kc < 256; kc += 32) {
            {
                const float* src = mn + (size_t)rowsel[si] * 256 + kc + skq;
                float4 v0 = *(const float4*)(src);
                float4 v1 = *(const float4*)(src + 16);
                As[skq + 0][si] = v0.x; As[skq + 1][si] = v0.y; As[skq + 2][si] = v0.z; As[skq + 3][si] = v0.w;
                As[skq + 16][si] = v1.x; As[skq + 17][si] = v1.y; As[skq + 18][si] = v1.z; As[skq + 19][si] = v1.w;
            }
            *(float4*)&Bs[sk][sj]      = *(const float4*)(mnT + (size_t)(kc + sk) * NROWPAD + j0 + sj);
            *(float4*)&Bs[sk + 16][sj] = *(const float4*)(mnT + (size_t)(kc + sk + 16) * NROWPAD + j0 + sj);
            __syncthreads();
#pragma unroll
            for (int k = 0; k < 32; k++) {
                float4 a4 = *(const float4*)&As[k][ty * 4];
                float4 b4 = *(const float4*)&Bs[k][tx * 4];
                float a[4] = {a4.x, a4.y, a4.z, a4.w}, b[4] = {b4.x, b4.y, b4.z, b4.w};
#pragma unroll
                for (int i = 0; i < 4; i++)
#pragma unroll
                    for (int j = 0; j < 4; j++) acc[i][j] = fmaf(a[i], b[j], acc[i][j]);
            }
            __syncthreads();
        }
#pragma unroll
        for (int j = 0; j < 4; j++) {
            int col = j0 + tx * 4 + j;
            if (col < N_ENT) {
#pragma unroll
                for (int i = 0; i < 4; i++) topk_insert(tv[i], ti[i], acc[i][j], col);
            }
        }
    }
    // cross-lane top-6 extraction: 6 rounds of shfl-xor argmax over the 16 tx lanes
#pragma unroll
    for (int i = 0; i < 4; i++) {
        int gr = n0 + ty * 4 + i;
        int used = 0;
#pragma unroll
        for (int s = 0; s < 6; s++) {
            float hv = sel6f(tv[i], used);
            int hi = sel6i(ti[i], used);
            float bv = hv; int bi = hi;
#pragma unroll
            for (int m = 1; m < 16; m <<= 1) {
                float ov = __shfl_xor(bv, m);
                int oi = __shfl_xor(bi, m);
                if (better(ov, oi, bv, bi)) { bv = ov; bi = oi; }
            }
            if (hi == bi) used++;  // col indices are unique across lanes
            if (tx == 0 && gr < N_ENT) {
                tval[((size_t)cs * N_ENT + gr) * 6 + s] = bv;
                tidx[((size_t)cs * N_ENT + gr) * 6 + s] = bi;
            }
        }
    }
}

__global__ __launch_bounds__(64) void p2_combine(const float* __restrict__ tval,
                                                 const int* __restrict__ tidx,
                                                 const float* __restrict__ denom,
                                                 const float* __restrict__ st, int c,
                                                 const float* __restrict__ rns,
                                                 const float* __restrict__ mn,
                                                 float* __restrict__ lsum) {
    const int n = blockIdx.x;
    __shared__ float sv[24];
    __shared__ int sidx[24];
    __shared__ int sel[6];
    int t = threadIdx.x;
    if (t < 24) {
        int cs = t / 6, s = t % 6;
        sv[t] = tval[((size_t)cs * N_ENT + n) * 6 + s];
        sidx[t] = tidx[((size_t)cs * N_ENT + n) * 6 + s];
    }
    __syncthreads();
    if (t == 0) {
        float pv = 1e30f; int pi = -1;
        for (int s = 0; s < 6; s++) {
            float bv = -1e30f; int bi = 0x7fffffff;
            for (int u = 0; u < 24; u++) {
                float v = sv[u]; int i = sidx[u];
                if (better(pv, pi, v, i) && better(v, i, bv, bi)) { bv = v; bi = i; }
            }
            sel[s] = bi;
            pv = bv; pi = bi;
        }
    }
    __syncthreads();
    float pos = 0.f;
    for (int s = 0; s < 6; s++) {
        const float* mr = mn + (size_t)sel[s] * 256;
        float d = 0.f;
        for (int dd = t; dd < 256; dd += 64)
            d += st[(size_t)n * 1280 + (size_t)dd * 5 + c] * mr[dd];
        for (int off = 32; off; off >>= 1) d += __shfl_down(d, off);
        if (t == 0) pos += __expf(d * rns[n] * INV_TAU);
    }
    if (t == 0) {
        float l = logf(denom[n]) - logf(pos);
        atomicAdd(lsum, l);
    }
}

__global__ void init_lsum(float* lsum) { lsum[0] = 0.f; }

__global__ void finalize_loss(const float* __restrict__ lsum, float* __restrict__ out) {
    out[12800000] = lsum[0] * (1.f / (N_ENT * 5.0f));
}

extern "C" void kernel_launch(void* const* d_in, const int* in_sizes, int n_in,
                              void* d_out, int out_size, void* d_ws, size_t ws_size,
                              hipStream_t stream) {
    (void)in_sizes; (void)n_in; (void)out_size; (void)ws_size;
    const float* st = (const float*)d_in[0];     // [10000][256][5]
    const float* mm = (const float*)d_in[1];     // [10000][768]
    const float* W1 = (const float*)d_in[2];     // [5][256][768]
    const float* b1 = (const float*)d_in[3];     // [5][256]
    const float* W2 = (const float*)d_in[4];     // [5][256][256]
    const float* b2 = (const float*)d_in[5];     // [5][256]
    const float* gamma = (const float*)d_in[6];  // [5][256]
    const float* beta = (const float*)d_in[7];   // [5][256]
    float* out = (float*)d_out;                  // 12.8M mm_out + 1 loss

    float* bufH = (float*)d_ws;                    // [5][10000][256] gelu(h1)
    float* bufE = bufH + 12800000ull;              // [5][10000][256] mm_enc (BN'd in place)
    float* fp = bufE + 12800000ull;
    float* bn_a = fp; fp += 1280;
    float* bn_b = fp; fp += 1280;
    float* rns = fp; fp += N_ENT;
    float* rnm = fp; fp += N_ENT;
    float* denom = fp; fp += N_ENT;
    float* pmax = fp; fp += 4 * N_ENT;
    float* psum = fp; fp += 4 * N_ENT;
    float* tval = fp; fp += 4 * N_ENT * 6;
    float* lsum = fp; fp += 8;
    int* ip = (int*)fp;
    int* amax = ip; ip += N_ENT;
    int* pidx = ip; ip += 4 * N_ENT;
    int* tidx = ip; ip += 4 * N_ENT * 6;
    // loss-stage buffers overlay bufH (free after GEMM2)
    float* snT = bufH;                     // [256][NROWPAD]
    float* mnT = bufH + 2572288ull;        // [256][NROWPAD]
    float* mn = bufH + 2ull * 2572288ull;  // [10000][256]

    init_lsum<<<1, 1, 0, stream>>>(lsum);

    dim3 gg(NTILES, 4, 5);
    enc_gemm<true><<<gg, 256, 0, stream>>>(mm, 0, W1, b1, bufH, N_ENT, 768);
    enc_gemm<false><<<gg, 256, 0, stream>>>(bufH, (size_t)N_ENT * 256, W2, b2, bufE, N_ENT, 256);

    bn_stats<<<1280, 256, 0, stream>>>(bufE, gamma, beta, bn_a, bn_b);
    bn_apply<<<50000, 256, 0, stream>>>(bufE, bn_a, bn_b, out);

    for (int c = 0; c < 5; c++) {
        rownorm<<<N_ENT, 256, 0, stream>>>(st + c, 1280, 5, rns);
        rownorm<<<N_ENT, 256, 0, stream>>>(bufE + (size_t)c * N_ENT * 256, 256, 1, rnm);
        build_snT<<<dim3(8, 313), dim3(32, 32), 0, stream>>>(st, c, rns, snT);
        build_mn<<<dim3(8, 313), dim3(32, 32), 0, stream>>>(bufE, c, rnm, mn, mnT);
        pass1<<<dim3(NTILES, CSPLIT), 256, 0, stream>>>(snT, mnT, pmax, pidx, psum);
        p1_combine<<<40, 256, 0, stream>>>(pmax, pidx, psum, amax, denom);
        pass2<<<dim3(NTILES, CSPLIT), 256, 0, stream>>>(mn, mnT, amax, tval, tidx);
        p2_combine<<<N_ENT, 64, 0, stream>>>(tval, tidx, denom, st, c, rns, mn, lsum);
    }
    finalize_loss<<<1, 1, 0, stream>>>(lsum, out);
}

// Round 4
// 3443.730 us; speedup vs baseline: 3.0724x; 3.0724x over previous
//
#include <hip/hip_runtime.h>
#include <hip/hip_bf16.h>
#include <math.h>

#define N_ENT 10000
#define NPAD 10112      // 79*128 padded rows for bf16 matrices
#define NCT 79          // column tiles of 128
#define CS1 8           // pass1 column split
#define CS2 4           // pass2 column split
#define INV_TAU 10.0f

typedef __attribute__((ext_vector_type(8))) short bf16x8;
typedef __attribute__((ext_vector_type(4))) float f32x4;

__device__ __forceinline__ bool better(float v, int i, float bv, int bi) {
    return (v > bv) || (v == bv && i < bi);
}

__device__ __forceinline__ float sel6f(const float (&a)[6], int k) {
    return k == 0 ? a[0] : k == 1 ? a[1] : k == 2 ? a[2] : k == 3 ? a[3] : k == 4 ? a[4] : a[5];
}
__device__ __forceinline__ int sel6i(const int (&a)[6], int k) {
    return k == 0 ? a[0] : k == 1 ? a[1] : k == 2 ? a[2] : k == 3 ? a[3] : k == 4 ? a[4] : a[5];
}

// Static (register-only) sorted-desc top-6 insert.
__device__ __forceinline__ void topk_insert(float (&v)[6], int (&ix)[6], float nv, int ni) {
    if (!better(nv, ni, v[5], ix[5])) return;
    bool b0 = better(v[0], ix[0], nv, ni);
    bool b1 = better(v[1], ix[1], nv, ni);
    bool b2 = better(v[2], ix[2], nv, ni);
    bool b3 = better(v[3], ix[3], nv, ni);
    bool b4 = better(v[4], ix[4], nv, ni);
    float o0 = v[0], o1 = v[1], o2 = v[2], o3 = v[3], o4 = v[4];
    int j0 = ix[0], j1 = ix[1], j2 = ix[2], j3 = ix[3], j4 = ix[4];
    v[0] = b0 ? o0 : nv;              ix[0] = b0 ? j0 : ni;
    v[1] = b1 ? o1 : (b0 ? nv : o0);  ix[1] = b1 ? j1 : (b0 ? ni : j0);
    v[2] = b2 ? o2 : (b1 ? nv : o1);  ix[2] = b2 ? j2 : (b1 ? ni : j1);
    v[3] = b3 ? o3 : (b2 ? nv : o2);  ix[3] = b3 ? j3 : (b2 ? ni : j2);
    v[4] = b4 ? o4 : (b3 ? nv : o3);  ix[4] = b4 ? j4 : (b3 ? ni : j3);
    v[5] = b4 ? nv : o4;              ix[5] = b4 ? ni : j4;
}

__device__ __forceinline__ ushort f2bf(float x) {
    __hip_bfloat16 h = __float2bfloat16(x);
    return *(ushort*)&h;
}

// ---------------- encoder GEMM (fp32, unchanged this round) ----------------
template <bool GELU>
__global__ __launch_bounds__(256) void enc_gemm(const float* __restrict__ A, size_t Astride,
                                                const float* __restrict__ B,
                                                const float* __restrict__ bias,
                                                float* __restrict__ C, int M, int K) {
    const int e = blockIdx.z;
    const float* Ae = A + (size_t)e * Astride;
    const float* Be = B + (size_t)e * 256 * K;
    const float* be = bias + e * 256;
    float* Ce = C + (size_t)e * (size_t)M * 256;
    const int n0 = blockIdx.x * 64;
    const int o0 = blockIdx.y * 64;
    __shared__ float As[16][64];
    __shared__ float Bs[16][64];
    const int tid = threadIdx.x;
    const int tx = tid & 15, ty = tid >> 4;
    const int li = tid >> 2;
    const int lk = (tid & 3) * 4;
    float acc[4][4];
#pragma unroll
    for (int i = 0; i < 4; i++)
#pragma unroll
        for (int j = 0; j < 4; j++) acc[i][j] = 0.f;
    for (int kc = 0; kc < K; kc += 16) {
        float4 av = make_float4(0.f, 0.f, 0.f, 0.f);
        if (n0 + li < M) av = *(const float4*)(Ae + (size_t)(n0 + li) * K + kc + lk);
        As[lk + 0][li] = av.x; As[lk + 1][li] = av.y; As[lk + 2][li] = av.z; As[lk + 3][li] = av.w;
        float4 bv = *(const float4*)(Be + (size_t)(o0 + li) * K + kc + lk);
        Bs[lk + 0][li] = bv.x; Bs[lk + 1][li] = bv.y; Bs[lk + 2][li] = bv.z; Bs[lk + 3][li] = bv.w;
        __syncthreads();
#pragma unroll
        for (int k = 0; k < 16; k++) {
            float4 a4 = *(const float4*)&As[k][ty * 4];
            float4 b4 = *(const float4*)&Bs[k][tx * 4];
            float a[4] = {a4.x, a4.y, a4.z, a4.w}, b[4] = {b4.x, b4.y, b4.z, b4.w};
#pragma unroll
            for (int i = 0; i < 4; i++)
#pragma unroll
                for (int j = 0; j < 4; j++) acc[i][j] = fmaf(a[i], b[j], acc[i][j]);
        }
        __syncthreads();
    }
#pragma unroll
    for (int i = 0; i < 4; i++) {
        int gr = n0 + ty * 4 + i;
        if (gr >= M) continue;
#pragma unroll
        for (int j = 0; j < 4; j++) {
            int go = o0 + tx * 4 + j;
            float v = acc[i][j] + be[go];
            if (GELU) v = 0.5f * v * (1.0f + erff(v * 0.70710678118654752f));
            Ce[(size_t)gr * 256 + go] = v;
        }
    }
}

// ---------------- BatchNorm ----------------
__global__ __launch_bounds__(256) void bn_stats(const float* __restrict__ E,
                                                const float* __restrict__ gamma,
                                                const float* __restrict__ beta,
                                                float* __restrict__ bn_a, float* __restrict__ bn_b) {
    const int ch = blockIdx.x;  // e*256+o
    const int e = ch >> 8, o = ch & 255;
    const float* p = E + (size_t)e * N_ENT * 256 + o;
    float s = 0.f, ss = 0.f;
    for (int n = threadIdx.x; n < N_ENT; n += 256) {
        float v = p[(size_t)n * 256];
        s += v; ss += v * v;
    }
    __shared__ float sh1[4], sh2[4];
    int lane = threadIdx.x & 63, w = threadIdx.x >> 6;
    for (int off = 32; off; off >>= 1) { s += __shfl_down(s, off); ss += __shfl_down(ss, off); }
    if (lane == 0) { sh1[w] = s; sh2[w] = ss; }
    __syncthreads();
    if (threadIdx.x == 0) {
        s = sh1[0] + sh1[1] + sh1[2] + sh1[3];
        ss = sh2[0] + sh2[1] + sh2[2] + sh2[3];
        float mu = s * (1.f / N_ENT);
        float var = ss * (1.f / N_ENT) - mu * mu;
        float r = rsqrtf(var + 1e-5f);
        float a = gamma[ch] * r;
        bn_a[ch] = a;
        bn_b[ch] = beta[ch] - mu * a;
    }
}

__global__ __launch_bounds__(256) void bn_apply(float* __restrict__ E,
                                                const float* __restrict__ bn_a,
                                                const float* __restrict__ bn_b,
                                                float* __restrict__ out) {
    size_t idx = (size_t)blockIdx.x * 256 + threadIdx.x;
    int e = (int)(idx / ((size_t)N_ENT * 256));
    size_t rem = idx - (size_t)e * N_ENT * 256;
    int n = (int)(rem >> 8), o = (int)(rem & 255);
    int ch = (e << 8) | o;
    float v = E[idx] * bn_a[ch] + bn_b[ch];
    E[idx] = v;
    out[(size_t)n * 1280 + o * 5 + e] = v;  // mm_out: [N][256][5]
}

// ---------------- per-comp prep ----------------
__global__ __launch_bounds__(256) void rownorm(const float* __restrict__ base, size_t rowstride,
                                               int elemstride, float* __restrict__ rn) {
    int n = blockIdx.x;
    float v = base[(size_t)n * rowstride + (size_t)threadIdx.x * elemstride];
    float s = v * v;
    __shared__ float sh[4];
    int lane = threadIdx.x & 63, w = threadIdx.x >> 6;
    for (int off = 32; off; off >>= 1) s += __shfl_down(s, off);
    if (lane == 0) sh[w] = s;
    __syncthreads();
    if (threadIdx.x == 0) {
        s = sh[0] + sh[1] + sh[2] + sh[3];
        rn[n] = 1.f / (sqrtf(s) + 1e-12f);
    }
}

// snb[n][o] = bf16(normalize(st[:, :, c])[n][o]), zero-padded rows to NPAD
__global__ __launch_bounds__(256) void build_snb(const float* __restrict__ st, int c,
                                                 const float* __restrict__ rns,
                                                 ushort* __restrict__ snb) {
    int n = blockIdx.x, o = threadIdx.x;
    float v = 0.f;
    if (n < N_ENT) v = st[(size_t)n * 1280 + o * 5 + c] * rns[n];
    snb[(size_t)n * 256 + o] = f2bf(v);
}

// mnb (bf16, padded) + mn (fp32, for p2_combine)
__global__ __launch_bounds__(256) void build_mnb(const float* __restrict__ E, int c,
                                                 const float* __restrict__ rnm,
                                                 ushort* __restrict__ mnb, float* __restrict__ mn) {
    int n = blockIdx.x, o = threadIdx.x;
    float v = 0.f;
    if (n < N_ENT) {
        v = E[((size_t)c * N_ENT + n) * 256 + o] * rnm[n];
        mn[(size_t)n * 256 + o] = v;
    }
    mnb[(size_t)n * 256 + o] = f2bf(v);
}

// ---------------- pass 1 (MFMA): per-row argmax + sum(exp(cos/tau)) ----------------
// BM=128 (4 waves x 32 rows), BN=128 col tiles, K=256. A in regs, B LDS-staged.
__global__ __launch_bounds__(256, 2) void pass1_mfma(const ushort* __restrict__ snb,
                                                     const ushort* __restrict__ mnb,
                                                     float* __restrict__ pmax, int* __restrict__ pidx,
                                                     float* __restrict__ psum) {
    __shared__ ushort Bs[128][72];  // 144B row stride: conflict-optimal b128 reads
    const int bx = blockIdx.x;      // 79 row blocks
    const int cs = blockIdx.y;      // 0..CS1-1
    const int tid = threadIdx.x;
    const int w = tid >> 6, lane = tid & 63;
    const int lr = lane & 15;       // A-row / B-col within fragment
    const int lg = lane >> 4;       // k-group (x8) / D row-group (x4)
    const int rbase = bx * 128 + w * 32;

    bf16x8 a[2][8];
#pragma unroll
    for (int rf = 0; rf < 2; rf++)
#pragma unroll
        for (int ks = 0; ks < 8; ks++)
            a[rf][ks] = *(const bf16x8*)(snb + (size_t)(rbase + rf * 16 + lr) * 256 + ks * 32 + lg * 8);

    float sume[2][4], maxv[2][4];
    int maxi[2][4];
#pragma unroll
    for (int rf = 0; rf < 2; rf++)
#pragma unroll
        for (int r = 0; r < 4; r++) { sume[rf][r] = 0.f; maxv[rf][r] = -1e30f; maxi[rf][r] = 0x7fffffff; }

    const int srow = tid >> 1;           // staging: row in B tile
    const int sp = (tid & 1) * 32;       // bf16 offset of this thread's 64B half

    for (int ct = cs; ct < NCT; ct += CS1) {
        const int c0 = ct * 128;
        f32x4 acc[2][8];
#pragma unroll
        for (int rf = 0; rf < 2; rf++)
#pragma unroll
            for (int fj = 0; fj < 8; fj++) acc[rf][fj] = (f32x4)(0.f);
        for (int kc = 0; kc < 4; kc++) {  // K-chunks of 64
            const ushort* gsrc = mnb + (size_t)(c0 + srow) * 256 + kc * 64 + sp;
            float4 g0 = *(const float4*)(gsrc);
            float4 g1 = *(const float4*)(gsrc + 8);
            float4 g2 = *(const float4*)(gsrc + 16);
            float4 g3 = *(const float4*)(gsrc + 24);
            __syncthreads();
            *(float4*)&Bs[srow][sp + 0] = g0;
            *(float4*)&Bs[srow][sp + 8] = g1;
            *(float4*)&Bs[srow][sp + 16] = g2;
            *(float4*)&Bs[srow][sp + 24] = g3;
            __syncthreads();
#pragma unroll
            for (int ki = 0; ki < 2; ki++) {
                const int ks = kc * 2 + ki;
#pragma unroll
                for (int fj = 0; fj < 8; fj++) {
                    bf16x8 b = *(const bf16x8*)&Bs[fj * 16 + lr][ki * 32 + lg * 8];
                    acc[0][fj] = __builtin_amdgcn_mfma_f32_16x16x32_bf16(a[0][ks], b, acc[0][fj], 0, 0, 0);
                    acc[1][fj] = __builtin_amdgcn_mfma_f32_16x16x32_bf16(a[1][ks], b, acc[1][fj], 0, 0, 0);
                }
            }
        }
#pragma unroll
        for (int fj = 0; fj < 8; fj++) {
            int col = c0 + fj * 16 + lr;
            bool ok = col < N_ENT;
#pragma unroll
            for (int rf = 0; rf < 2; rf++)
#pragma unroll
                for (int r = 0; r < 4; r++) {
                    float v = acc[rf][fj][r];
                    if (ok) {
                        sume[rf][r] += __expf(v * INV_TAU);
                        if (v > maxv[rf][r]) { maxv[rf][r] = v; maxi[rf][r] = col; }
                    }
                }
        }
    }
#pragma unroll
    for (int m = 1; m < 16; m <<= 1) {
#pragma unroll
        for (int rf = 0; rf < 2; rf++)
#pragma unroll
            for (int r = 0; r < 4; r++) {
                float ov = __shfl_xor(maxv[rf][r], m);
                int oi = __shfl_xor(maxi[rf][r], m);
                float os = __shfl_xor(sume[rf][r], m);
                sume[rf][r] += os;
                if (better(ov, oi, maxv[rf][r], maxi[rf][r])) { maxv[rf][r] = ov; maxi[rf][r] = oi; }
            }
    }
    if (lr == 0) {
#pragma unroll
        for (int rf = 0; rf < 2; rf++)
#pragma unroll
            for (int r = 0; r < 4; r++) {
                int gr = rbase + rf * 16 + 4 * lg + r;
                if (gr < N_ENT) {
                    pmax[(size_t)cs * N_ENT + gr] = maxv[rf][r];
                    pidx[(size_t)cs * N_ENT + gr] = maxi[rf][r];
                    psum[(size_t)cs * N_ENT + gr] = sume[rf][r];
                }
            }
    }
}

__global__ __launch_bounds__(256) void p1_combine(const float* __restrict__ pmax,
                                                  const int* __restrict__ pidx,
                                                  const float* __restrict__ psum,
                                                  int* __restrict__ amax, float* __restrict__ denom) {
    int n = blockIdx.x * 256 + threadIdx.x;
    if (n >= N_ENT) return;
    float bm = -1e30f; int bi = 0x7fffffff; float s = 0.f;
    for (int cs = 0; cs < CS1; cs++) {
        float v = pmax[(size_t)cs * N_ENT + n];
        int ii = pidx[(size_t)cs * N_ENT + n];
        s += psum[(size_t)cs * N_ENT + n];
        if (v > bm || (v == bm && ii < bi)) { bm = v; bi = ii; }
    }
    amax[n] = bi;
    denom[n] = s;
}

// ---------------- pass 2 (MFMA): rows = mn[amax] @ mn^T, streaming top-6 ----------------
// BM=64 (4 waves x 16 rows), BN=128 col tiles, K=256.
__global__ __launch_bounds__(256, 2) void pass2_mfma(const ushort* __restrict__ mnb,
                                                     const int* __restrict__ amax,
                                                     float* __restrict__ tval, int* __restrict__ tidx) {
    __shared__ ushort Bs[128][72];
    __shared__ int rowsel[64];
    const int bx = blockIdx.x;   // 158 row blocks
    const int cs = blockIdx.y;   // 0..CS2-1
    const int tid = threadIdx.x;
    const int w = tid >> 6, lane = tid & 63;
    const int lr = lane & 15;
    const int lg = lane >> 4;
    const int rbase = bx * 64 + w * 16;
    if (tid < 64) {
        int g = bx * 64 + tid;
        rowsel[tid] = (g < N_ENT) ? amax[g] : 0;
    }
    __syncthreads();

    bf16x8 a[8];
    {
        int src = rowsel[w * 16 + lr];
#pragma unroll
        for (int ks = 0; ks < 8; ks++)
            a[ks] = *(const bf16x8*)(mnb + (size_t)src * 256 + ks * 32 + lg * 8);
    }
    float tv[4][6]; int ti[4][6];
#pragma unroll
    for (int r = 0; r < 4; r++)
#pragma unroll
        for (int s = 0; s < 6; s++) { tv[r][s] = -1e30f; ti[r][s] = 0x7fffffff; }

    const int srow = tid >> 1;
    const int sp = (tid & 1) * 32;

    for (int ct = cs; ct < NCT; ct += CS2) {
        const int c0 = ct * 128;
        f32x4 acc[8];
#pragma unroll
        for (int fj = 0; fj < 8; fj++) acc[fj] = (f32x4)(0.f);
        for (int kc = 0; kc < 4; kc++) {
            const ushort* gsrc = mnb + (size_t)(c0 + srow) * 256 + kc * 64 + sp;
            float4 g0 = *(const float4*)(gsrc);
            float4 g1 = *(const float4*)(gsrc + 8);
            float4 g2 = *(const float4*)(gsrc + 16);
            float4 g3 = *(const float4*)(gsrc + 24);
            __syncthreads();
            *(float4*)&Bs[srow][sp + 0] = g0;
            *(float4*)&Bs[srow][sp + 8] = g1;
            *(float4*)&Bs[srow][sp + 16] = g2;
            *(float4*)&Bs[srow][sp + 24] = g3;
            __syncthreads();
#pragma unroll
            for (int ki = 0; ki < 2; ki++) {
                const int ks = kc * 2 + ki;
#pragma unroll
                for (int fj = 0; fj < 8; fj++) {
                    bf16x8 b = *(const bf16x8*)&Bs[fj * 16 + lr][ki * 32 + lg * 8];
                    acc[fj] = __builtin_amdgcn_mfma_f32_16x16x32_bf16(a[ks], b, acc[fj], 0, 0, 0);
                }
            }
        }
#pragma unroll
        for (int fj = 0; fj < 8; fj++) {
            int col = c0 + fj * 16 + lr;
            if (col < N_ENT) {
#pragma unroll
                for (int r = 0; r < 4; r++) topk_insert(tv[r], ti[r], acc[fj][r], col);
            }
        }
    }
    // cross-lane top-6 extraction over the 16 column-owning lanes (masks < 16)
#pragma unroll
    for (int r = 0; r < 4; r++) {
        int gr = rbase + 4 * lg + r;
        int used = 0;
#pragma unroll
        for (int s = 0; s < 6; s++) {
            float hv = sel6f(tv[r], used);
            int hi = sel6i(ti[r], used);
            float bv = hv; int bi = hi;
#pragma unroll
            for (int m = 1; m < 16; m <<= 1) {
                float ov = __shfl_xor(bv, m);
                int oi = __shfl_xor(bi, m);
                if (better(ov, oi, bv, bi)) { bv = ov; bi = oi; }
            }
            if (hi == bi) used++;  // col indices unique across lanes
            if (lr == 0 && gr < N_ENT) {
                tval[((size_t)cs * N_ENT + gr) * 6 + s] = bv;
                tidx[((size_t)cs * N_ENT + gr) * 6 + s] = bi;
            }
        }
    }
}

__global__ __launch_bounds__(64) void p2_combine(const float* __restrict__ tval,
                                                 const int* __restrict__ tidx,
                                                 const float* __restrict__ denom,
                                                 const float* __restrict__ st, int c,
                                                 const float* __restrict__ rns,
                                                 const float* __restrict__ mn,
                                                 float* __restrict__ lsum) {
    const int n = blockIdx.x;
    __shared__ float sv[24];
    __shared__ int sidx[24];
    __shared__ int sel[6];
    int t = threadIdx.x;
    if (t < 24) {
        int cs = t / 6, s = t % 6;
        sv[t] = tval[((size_t)cs * N_ENT + n) * 6 + s];
        sidx[t] = tidx[((size_t)cs * N_ENT + n) * 6 + s];
    }
    __syncthreads();
    if (t == 0) {
        float pv = 1e30f; int pi = -1;
        for (int s = 0; s < 6; s++) {
            float bv = -1e30f; int bi = 0x7fffffff;
            for (int u = 0; u < 24; u++) {
                float v = sv[u]; int i = sidx[u];
                if (better(pv, pi, v, i) && better(v, i, bv, bi)) { bv = v; bi = i; }
            }
            sel[s] = bi;
            pv = bv; pi = bi;
        }
    }
    __syncthreads();
    float pos = 0.f;
    for (int s = 0; s < 6; s++) {
        const float* mr = mn + (size_t)sel[s] * 256;
        float d = 0.f;
        for (int dd = t; dd < 256; dd += 64)
            d += st[(size_t)n * 1280 + (size_t)dd * 5 + c] * mr[dd];
        for (int off = 32; off; off >>= 1) d += __shfl_down(d, off);
        if (t == 0) pos += __expf(d * rns[n] * INV_TAU);
    }
    if (t == 0) {
        float l = logf(denom[n]) - logf(pos);
        atomicAdd(lsum, l);
    }
}

__global__ void init_lsum(float* lsum) { lsum[0] = 0.f; }

__global__ void finalize_loss(const float* __restrict__ lsum, float* __restrict__ out) {
    out[12800000] = lsum[0] * (1.f / (N_ENT * 5.0f));
}

extern "C" void kernel_launch(void* const* d_in, const int* in_sizes, int n_in,
                              void* d_out, int out_size, void* d_ws, size_t ws_size,
                              hipStream_t stream) {
    (void)in_sizes; (void)n_in; (void)out_size; (void)ws_size;
    const float* st = (const float*)d_in[0];     // [10000][256][5]
    const float* mm = (const float*)d_in[1];     // [10000][768]
    const float* W1 = (const float*)d_in[2];     // [5][256][768]
    const float* b1 = (const float*)d_in[3];     // [5][256]
    const float* W2 = (const float*)d_in[4];     // [5][256][256]
    const float* b2 = (const float*)d_in[5];     // [5][256]
    const float* gamma = (const float*)d_in[6];  // [5][256]
    const float* beta = (const float*)d_in[7];   // [5][256]
    float* out = (float*)d_out;                  // 12.8M mm_out + 1 loss

    float* bufH = (float*)d_ws;                    // [5][10000][256] gelu(h1)
    float* bufE = bufH + 12800000ull;              // [5][10000][256] mm_enc (BN'd in place)
    float* fp = bufE + 12800000ull;
    float* bn_a = fp; fp += 1280;
    float* bn_b = fp; fp += 1280;
    float* rns = fp; fp += N_ENT;
    float* rnm = fp; fp += N_ENT;
    float* denom = fp; fp += N_ENT;
    float* pmax = fp; fp += CS1 * N_ENT;
    float* psum = fp; fp += CS1 * N_ENT;
    float* tval = fp; fp += CS2 * N_ENT * 6;
    float* lsum = fp; fp += 8;
    int* ip = (int*)fp;
    int* amax = ip; ip += N_ENT;
    int* pidx = ip; ip += CS1 * N_ENT;
    int* tidx = ip; ip += CS2 * N_ENT * 6;
    // loss-stage buffers overlay bufH (free after enc_gemm<false>)
    float* mn = bufH;                              // [10000][256] fp32
    ushort* snb = (ushort*)(bufH + 2560000);       // [NPAD][256] bf16
    ushort* mnb = snb + (size_t)NPAD * 256;        // [NPAD][256] bf16

    init_lsum<<<1, 1, 0, stream>>>(lsum);

    dim3 gg(157, 4, 5);
    enc_gemm<true><<<gg, 256, 0, stream>>>(mm, 0, W1, b1, bufH, N_ENT, 768);
    enc_gemm<false><<<gg, 256, 0, stream>>>(bufH, (size_t)N_ENT * 256, W2, b2, bufE, N_ENT, 256);

    bn_stats<<<1280, 256, 0, stream>>>(bufE, gamma, beta, bn_a, bn_b);
    bn_apply<<<50000, 256, 0, stream>>>(bufE, bn_a, bn_b, out);

    for (int c = 0; c < 5; c++) {
        rownorm<<<N_ENT, 256, 0, stream>>>(st + c, 1280, 5, rns);
        rownorm<<<N_ENT, 256, 0, stream>>>(bufE + (size_t)c * N_ENT * 256, 256, 1, rnm);
        build_snb<<<NPAD, 256, 0, stream>>>(st, c, rns, snb);
        build_mnb<<<NPAD, 256, 0, stream>>>(bufE, c, rnm, mnb, mn);
        pass1_mfma<<<dim3(NPAD / 128, CS1), 256, 0, stream>>>(snb, mnb, pmax, pidx, psum);
        p1_combine<<<40, 256, 0, stream>>>(pmax, pidx, psum, amax, denom);
        pass2_mfma<<<dim3(NPAD / 64, CS2), 256, 0, stream>>>(mnb, amax, tval, tidx);
        p2_combine<<<N_ENT, 64, 0, stream>>>(tval, tidx, denom, st, c, rns, mn, lsum);
    }
    finalize_loss<<<1, 1, 0, stream>>>(lsum, out);
}

// Round 5
// 3399.792 us; speedup vs baseline: 3.1121x; 1.0129x over previous
//
#include <hip/hip_runtime.h>
#include <hip/hip_bf16.h>
#include <math.h>

#define N_ENT 10000
#define NPAD 10112      // 79*128 padded rows for bf16 matrices
#define NCT 79          // column tiles of 128
#define CS1 13          // pass1 column split (1027 blocks ~ 2 full occupancy rounds)
#define CS2 13          // pass2 column split (2054 blocks)
#define INV_TAU 10.0f

typedef __attribute__((ext_vector_type(8))) short bf16x8;
typedef __attribute__((ext_vector_type(4))) float f32x4;

__device__ __forceinline__ bool better(float v, int i, float bv, int bi) {
    return (v > bv) || (v == bv && i < bi);
}

__device__ __forceinline__ float sel6f(const float (&a)[6], int k) {
    return k == 0 ? a[0] : k == 1 ? a[1] : k == 2 ? a[2] : k == 3 ? a[3] : k == 4 ? a[4] : a[5];
}
__device__ __forceinline__ int sel6i(const int (&a)[6], int k) {
    return k == 0 ? a[0] : k == 1 ? a[1] : k == 2 ? a[2] : k == 3 ? a[3] : k == 4 ? a[4] : a[5];
}

// Static (register-only) sorted-desc top-6 insert.
__device__ __forceinline__ void topk_insert(float (&v)[6], int (&ix)[6], float nv, int ni) {
    if (!better(nv, ni, v[5], ix[5])) return;
    bool b0 = better(v[0], ix[0], nv, ni);
    bool b1 = better(v[1], ix[1], nv, ni);
    bool b2 = better(v[2], ix[2], nv, ni);
    bool b3 = better(v[3], ix[3], nv, ni);
    bool b4 = better(v[4], ix[4], nv, ni);
    float o0 = v[0], o1 = v[1], o2 = v[2], o3 = v[3], o4 = v[4];
    int j0 = ix[0], j1 = ix[1], j2 = ix[2], j3 = ix[3], j4 = ix[4];
    v[0] = b0 ? o0 : nv;              ix[0] = b0 ? j0 : ni;
    v[1] = b1 ? o1 : (b0 ? nv : o0);  ix[1] = b1 ? j1 : (b0 ? ni : j0);
    v[2] = b2 ? o2 : (b1 ? nv : o1);  ix[2] = b2 ? j2 : (b1 ? ni : j1);
    v[3] = b3 ? o3 : (b2 ? nv : o2);  ix[3] = b3 ? j3 : (b2 ? ni : j2);
    v[4] = b4 ? o4 : (b3 ? nv : o3);  ix[4] = b4 ? j4 : (b3 ? ni : j3);
    v[5] = b4 ? nv : o4;              ix[5] = b4 ? ni : j4;
}

__device__ __forceinline__ ushort f2bf(float x) {
    __hip_bfloat16 h = __float2bfloat16(x);
    return *(ushort*)&h;
}
__device__ __forceinline__ float bf2f(ushort h) {
    unsigned int u = ((unsigned int)h) << 16;
    return __uint_as_float(u);
}

// ---------------- weight split-bf16 conversion (once per launch) ----------------
__global__ __launch_bounds__(256) void conv_w(const float* __restrict__ w, ushort* __restrict__ hi,
                                              ushort* __restrict__ lo, int n) {
    int i = blockIdx.x * 256 + threadIdx.x;
    if (i >= n) return;
    float v = w[i];
    ushort h = f2bf(v);
    hi[i] = h;
    lo[i] = f2bf(v - bf2f(h));
}

// ---------------- encoder GEMM: 3-term split-bf16 MFMA ----------------
// C[e][n][o] = act(sum_k A[n][k] W[e][o][k] + b[e][o]); A fp32 converted hi/lo in staging.
// Tile: 128 rows x 128 cols, 4 waves (each 32 rows x 128 cols), K-chunks of 32.
template <bool GELU>
__global__ __launch_bounds__(256, 2) void enc_mfma(const float* __restrict__ A, size_t Astride, int K,
                                                   const ushort* __restrict__ Whi,
                                                   const ushort* __restrict__ Wlo,
                                                   const float* __restrict__ bias,
                                                   float* __restrict__ C) {
    __shared__ ushort Ah[128][40], Al[128][40], Bh[128][40], Bl[128][40];
    const int e = blockIdx.z;
    const float* Ae = A + (size_t)e * Astride;
    const ushort* Whe = Whi + (size_t)e * 256 * K;
    const ushort* Wle = Wlo + (size_t)e * 256 * K;
    const float* be = bias + e * 256;
    float* Ce = C + (size_t)e * N_ENT * 256;
    const int n0 = blockIdx.x * 128;
    const int o0 = blockIdx.y * 128;
    const int tid = threadIdx.x;
    const int w = tid >> 6, lane = tid & 63;
    const int lr = lane & 15, lg = lane >> 4;
    // staging mapping: thread pair per row; each thread 16 K-elements
    const int srow = tid >> 1;
    const int skf = (tid & 1) * 16;

    f32x4 acc[2][8];
#pragma unroll
    for (int rf = 0; rf < 2; rf++)
#pragma unroll
        for (int fj = 0; fj < 8; fj++) acc[rf][fj] = (f32x4)(0.f);

    const int nkc = K >> 5;
    float4 ga[4];
    uint4 gwh[2], gwl[2];
    const bool rowok = (n0 + srow) < N_ENT;

#define ENC_ISSUE(KC)                                                                  \
    {                                                                                  \
        const float* ap = Ae + (size_t)(n0 + srow) * K + (KC) * 32 + skf;              \
        if (rowok) {                                                                   \
            ga[0] = *(const float4*)(ap + 0);  ga[1] = *(const float4*)(ap + 4);       \
            ga[2] = *(const float4*)(ap + 8);  ga[3] = *(const float4*)(ap + 12);      \
        } else {                                                                       \
            ga[0] = ga[1] = ga[2] = ga[3] = make_float4(0.f, 0.f, 0.f, 0.f);           \
        }                                                                              \
        const ushort* hp = Whe + (size_t)(o0 + srow) * K + (KC) * 32 + skf;            \
        gwh[0] = *(const uint4*)(hp); gwh[1] = *(const uint4*)(hp + 8);                \
        const ushort* lp = Wle + (size_t)(o0 + srow) * K + (KC) * 32 + skf;            \
        gwl[0] = *(const uint4*)(lp); gwl[1] = *(const uint4*)(lp + 8);                \
    }

    ENC_ISSUE(0)
    for (int kc = 0; kc < nkc; kc++) {
        __syncthreads();
#pragma unroll
        for (int j = 0; j < 4; j++) {
            float4 v = ga[j];
            ushort h0 = f2bf(v.x), h1 = f2bf(v.y), h2 = f2bf(v.z), h3 = f2bf(v.w);
            ushort l0 = f2bf(v.x - bf2f(h0)), l1 = f2bf(v.y - bf2f(h1));
            ushort l2 = f2bf(v.z - bf2f(h2)), l3 = f2bf(v.w - bf2f(h3));
            *(ushort4*)&Ah[srow][skf + j * 4] = make_ushort4(h0, h1, h2, h3);
            *(ushort4*)&Al[srow][skf + j * 4] = make_ushort4(l0, l1, l2, l3);
        }
        *(uint4*)&Bh[srow][skf] = gwh[0];
        *(uint4*)&Bh[srow][skf + 8] = gwh[1];
        *(uint4*)&Bl[srow][skf] = gwl[0];
        *(uint4*)&Bl[srow][skf + 8] = gwl[1];
        __syncthreads();
        if (kc + 1 < nkc) ENC_ISSUE(kc + 1)
        bf16x8 ah[2], al[2];
#pragma unroll
        for (int rf = 0; rf < 2; rf++) {
            ah[rf] = *(const bf16x8*)&Ah[w * 32 + rf * 16 + lr][lg * 8];
            al[rf] = *(const bf16x8*)&Al[w * 32 + rf * 16 + lr][lg * 8];
        }
#pragma unroll
        for (int fj = 0; fj < 8; fj++) {
            bf16x8 bh = *(const bf16x8*)&Bh[fj * 16 + lr][lg * 8];
            bf16x8 bl = *(const bf16x8*)&Bl[fj * 16 + lr][lg * 8];
#pragma unroll
            for (int rf = 0; rf < 2; rf++) {
                acc[rf][fj] = __builtin_amdgcn_mfma_f32_16x16x32_bf16(ah[rf], bh, acc[rf][fj], 0, 0, 0);
                acc[rf][fj] = __builtin_amdgcn_mfma_f32_16x16x32_bf16(ah[rf], bl, acc[rf][fj], 0, 0, 0);
                acc[rf][fj] = __builtin_amdgcn_mfma_f32_16x16x32_bf16(al[rf], bh, acc[rf][fj], 0, 0, 0);
            }
        }
    }
#undef ENC_ISSUE
#pragma unroll
    for (int rf = 0; rf < 2; rf++) {
#pragma unroll
        for (int r = 0; r < 4; r++) {
            int gr = n0 + w * 32 + rf * 16 + 4 * lg + r;
            if (gr >= N_ENT) continue;
#pragma unroll
            for (int fj = 0; fj < 8; fj++) {
                int go = o0 + fj * 16 + lr;
                float v = acc[rf][fj][r] + be[go];
                if (GELU) v = 0.5f * v * (1.0f + erff(v * 0.70710678118654752f));
                Ce[(size_t)gr * 256 + go] = v;
            }
        }
    }
}

// ---------------- BatchNorm: two-stage coalesced stats ----------------
__global__ __launch_bounds__(256) void bn_part(const float* __restrict__ E,
                                               float* __restrict__ ps, float* __restrict__ pss) {
    const int e = blockIdx.x, chunk = blockIdx.y;  // 5 x 40, 250 rows each
    const float* base = E + ((size_t)e * N_ENT + (size_t)chunk * 250) * 256;
    const int o = threadIdx.x;
    float s = 0.f, ss = 0.f;
    for (int r = 0; r < 250; r++) {
        float v = base[(size_t)r * 256 + o];
        s += v; ss += v * v;
    }
    ps[((size_t)e * 40 + chunk) * 256 + o] = s;
    pss[((size_t)e * 40 + chunk) * 256 + o] = ss;
}

__global__ __launch_bounds__(256) void bn_finish(const float* __restrict__ ps,
                                                 const float* __restrict__ pss,
                                                 const float* __restrict__ gamma,
                                                 const float* __restrict__ beta,
                                                 float* __restrict__ bn_a, float* __restrict__ bn_b) {
    const int e = blockIdx.x, o = threadIdx.x;
    float s = 0.f, ss = 0.f;
    for (int c = 0; c < 40; c++) {
        s += ps[((size_t)e * 40 + c) * 256 + o];
        ss += pss[((size_t)e * 40 + c) * 256 + o];
    }
    float mu = s * (1.f / N_ENT);
    float var = ss * (1.f / N_ENT) - mu * mu;
    float r = rsqrtf(var + 1e-5f);
    int ch = e * 256 + o;
    float a = gamma[ch] * r;
    bn_a[ch] = a;
    bn_b[ch] = beta[ch] - mu * a;
}

__global__ __launch_bounds__(256) void bn_apply(float* __restrict__ E,
                                                const float* __restrict__ bn_a,
                                                const float* __restrict__ bn_b,
                                                float* __restrict__ out) {
    size_t idx = (size_t)blockIdx.x * 256 + threadIdx.x;
    int e = (int)(idx / ((size_t)N_ENT * 256));
    size_t rem = idx - (size_t)e * N_ENT * 256;
    int n = (int)(rem >> 8), o = (int)(rem & 255);
    int ch = (e << 8) | o;
    float v = E[idx] * bn_a[ch] + bn_b[ch];
    E[idx] = v;
    out[(size_t)n * 1280 + o * 5 + e] = v;  // mm_out: [N][256][5]
}

// ---------------- per-comp prep ----------------
__global__ __launch_bounds__(256) void rownorm(const float* __restrict__ base, size_t rowstride,
                                               int elemstride, float* __restrict__ rn) {
    int n = blockIdx.x;
    float v = base[(size_t)n * rowstride + (size_t)threadIdx.x * elemstride];
    float s = v * v;
    __shared__ float sh[4];
    int lane = threadIdx.x & 63, w = threadIdx.x >> 6;
    for (int off = 32; off; off >>= 1) s += __shfl_down(s, off);
    if (lane == 0) sh[w] = s;
    __syncthreads();
    if (threadIdx.x == 0) {
        s = sh[0] + sh[1] + sh[2] + sh[3];
        rn[n] = 1.f / (sqrtf(s) + 1e-12f);
    }
}

__global__ __launch_bounds__(256) void build_snb(const float* __restrict__ st, int c,
                                                 const float* __restrict__ rns,
                                                 ushort* __restrict__ snb) {
    int n = blockIdx.x, o = threadIdx.x;
    float v = 0.f;
    if (n < N_ENT) v = st[(size_t)n * 1280 + o * 5 + c] * rns[n];
    snb[(size_t)n * 256 + o] = f2bf(v);
}

__global__ __launch_bounds__(256) void build_mnb(const float* __restrict__ E, int c,
                                                 const float* __restrict__ rnm,
                                                 ushort* __restrict__ mnb, float* __restrict__ mn) {
    int n = blockIdx.x, o = threadIdx.x;
    float v = 0.f;
    if (n < N_ENT) {
        v = E[((size_t)c * N_ENT + n) * 256 + o] * rnm[n];
        mn[(size_t)n * 256 + o] = v;
    }
    mnb[(size_t)n * 256 + o] = f2bf(v);
}

#define P_ISSUE(CT, KC)                                                                  \
    {                                                                                    \
        const ushort* gsrc = mnb + (size_t)((CT) * 128 + srow) * 256 + (KC) * 64 + sp;   \
        g0 = *(const float4*)(gsrc);       g1 = *(const float4*)(gsrc + 8);              \
        g2 = *(const float4*)(gsrc + 16);  g3 = *(const float4*)(gsrc + 24);             \
    }

// ---------------- pass 1 (MFMA): per-row argmax + sum(exp(cos/tau)) ----------------
__global__ __launch_bounds__(256, 2) void pass1_mfma(const ushort* __restrict__ snb,
                                                     const ushort* __restrict__ mnb,
                                                     float* __restrict__ pmax, int* __restrict__ pidx,
                                                     float* __restrict__ psum) {
    __shared__ ushort Bs[128][72];
    const int bx = blockIdx.x;
    const int cs = blockIdx.y;
    const int tid = threadIdx.x;
    const int w = tid >> 6, lane = tid & 63;
    const int lr = lane & 15;
    const int lg = lane >> 4;
    const int rbase = bx * 128 + w * 32;

    bf16x8 a[2][8];
#pragma unroll
    for (int rf = 0; rf < 2; rf++)
#pragma unroll
        for (int ks = 0; ks < 8; ks++)
            a[rf][ks] = *(const bf16x8*)(snb + (size_t)(rbase + rf * 16 + lr) * 256 + ks * 32 + lg * 8);

    float sume[2][4], maxv[2][4];
    int maxi[2][4];
#pragma unroll
    for (int rf = 0; rf < 2; rf++)
#pragma unroll
        for (int r = 0; r < 4; r++) { sume[rf][r] = 0.f; maxv[rf][r] = -1e30f; maxi[rf][r] = 0x7fffffff; }

    const int srow = tid >> 1;
    const int sp = (tid & 1) * 32;
    float4 g0, g1, g2, g3;

    P_ISSUE(cs, 0)
    for (int ct = cs; ct < NCT; ct += CS1) {
        const int c0 = ct * 128;
        f32x4 acc[2][8];
#pragma unroll
        for (int rf = 0; rf < 2; rf++)
#pragma unroll
            for (int fj = 0; fj < 8; fj++) acc[rf][fj] = (f32x4)(0.f);
        for (int kc = 0; kc < 4; kc++) {
            __syncthreads();
            *(float4*)&Bs[srow][sp + 0] = g0;
            *(float4*)&Bs[srow][sp + 8] = g1;
            *(float4*)&Bs[srow][sp + 16] = g2;
            *(float4*)&Bs[srow][sp + 24] = g3;
            __syncthreads();
            {   // issue next chunk's loads (hidden under MFMA below)
                int nct = ct, nkc = kc + 1;
                if (nkc == 4) { nkc = 0; nct = ct + CS1; }
                if (nct < NCT) P_ISSUE(nct, nkc)
            }
#pragma unroll
            for (int ki = 0; ki < 2; ki++) {
                const int ks = kc * 2 + ki;
#pragma unroll
                for (int fj = 0; fj < 8; fj++) {
                    bf16x8 b = *(const bf16x8*)&Bs[fj * 16 + lr][ki * 32 + lg * 8];
                    acc[0][fj] = __builtin_amdgcn_mfma_f32_16x16x32_bf16(a[0][ks], b, acc[0][fj], 0, 0, 0);
                    acc[1][fj] = __builtin_amdgcn_mfma_f32_16x16x32_bf16(a[1][ks], b, acc[1][fj], 0, 0, 0);
                }
            }
        }
#pragma unroll
        for (int fj = 0; fj < 8; fj++) {
            int col = c0 + fj * 16 + lr;
            bool ok = col < N_ENT;
#pragma unroll
            for (int rf = 0; rf < 2; rf++)
#pragma unroll
                for (int r = 0; r < 4; r++) {
                    float v = acc[rf][fj][r];
                    if (ok) {
                        sume[rf][r] += __expf(v * INV_TAU);
                        if (v > maxv[rf][r]) { maxv[rf][r] = v; maxi[rf][r] = col; }
                    }
                }
        }
    }
#pragma unroll
    for (int m = 1; m < 16; m <<= 1) {
#pragma unroll
        for (int rf = 0; rf < 2; rf++)
#pragma unroll
            for (int r = 0; r < 4; r++) {
                float ov = __shfl_xor(maxv[rf][r], m);
                int oi = __shfl_xor(maxi[rf][r], m);
                float os = __shfl_xor(sume[rf][r], m);
                sume[rf][r] += os;
                if (better(ov, oi, maxv[rf][r], maxi[rf][r])) { maxv[rf][r] = ov; maxi[rf][r] = oi; }
            }
    }
    if (lr == 0) {
#pragma unroll
        for (int rf = 0; rf < 2; rf++)
#pragma unroll
            for (int r = 0; r < 4; r++) {
                int gr = rbase + rf * 16 + 4 * lg + r;
                if (gr < N_ENT) {
                    pmax[(size_t)cs * N_ENT + gr] = maxv[rf][r];
                    pidx[(size_t)cs * N_ENT + gr] = maxi[rf][r];
                    psum[(size_t)cs * N_ENT + gr] = sume[rf][r];
                }
            }
    }
}

__global__ __launch_bounds__(256) void p1_combine(const float* __restrict__ pmax,
                                                  const int* __restrict__ pidx,
                                                  const float* __restrict__ psum,
                                                  int* __restrict__ amax, float* __restrict__ denom) {
    int n = blockIdx.x * 256 + threadIdx.x;
    if (n >= N_ENT) return;
    float bm = -1e30f; int bi = 0x7fffffff; float s = 0.f;
    for (int cs = 0; cs < CS1; cs++) {
        float v = pmax[(size_t)cs * N_ENT + n];
        int ii = pidx[(size_t)cs * N_ENT + n];
        s += psum[(size_t)cs * N_ENT + n];
        if (v > bm || (v == bm && ii < bi)) { bm = v; bi = ii; }
    }
    amax[n] = bi;
    denom[n] = s;
}

// ---------------- pass 2 (MFMA): rows = mn[amax] @ mn^T, streaming top-6 ----------------
__global__ __launch_bounds__(256, 2) void pass2_mfma(const ushort* __restrict__ mnb,
                                                     const int* __restrict__ amax,
                                                     float* __restrict__ tval, int* __restrict__ tidx) {
    __shared__ ushort Bs[128][72];
    __shared__ int rowsel[64];
    const int bx = blockIdx.x;
    const int cs = blockIdx.y;
    const int tid = threadIdx.x;
    const int w = tid >> 6, lane = tid & 63;
    const int lr = lane & 15;
    const int lg = lane >> 4;
    const int rbase = bx * 64 + w * 16;
    if (tid < 64) {
        int g = bx * 64 + tid;
        rowsel[tid] = (g < N_ENT) ? amax[g] : 0;
    }
    __syncthreads();

    bf16x8 a[8];
    {
        int src = rowsel[w * 16 + lr];
#pragma unroll
        for (int ks = 0; ks < 8; ks++)
            a[ks] = *(const bf16x8*)(mnb + (size_t)src * 256 + ks * 32 + lg * 8);
    }
    float tv[4][6]; int ti[4][6];
#pragma unroll
    for (int r = 0; r < 4; r++)
#pragma unroll
        for (int s = 0; s < 6; s++) { tv[r][s] = -1e30f; ti[r][s] = 0x7fffffff; }

    const int srow = tid >> 1;
    const int sp = (tid & 1) * 32;
    float4 g0, g1, g2, g3;

    P_ISSUE(cs, 0)
    for (int ct = cs; ct < NCT; ct += CS2) {
        const int c0 = ct * 128;
        f32x4 acc[8];
#pragma unroll
        for (int fj = 0; fj < 8; fj++) acc[fj] = (f32x4)(0.f);
        for (int kc = 0; kc < 4; kc++) {
            __syncthreads();
            *(float4*)&Bs[srow][sp + 0] = g0;
            *(float4*)&Bs[srow][sp + 8] = g1;
            *(float4*)&Bs[srow][sp + 16] = g2;
            *(float4*)&Bs[srow][sp + 24] = g3;
            __syncthreads();
            {
                int nct = ct, nkc = kc + 1;
                if (nkc == 4) { nkc = 0; nct = ct + CS2; }
                if (nct < NCT) P_ISSUE(nct, nkc)
            }
#pragma unroll
            for (int ki = 0; ki < 2; ki++) {
                const int ks = kc * 2 + ki;
#pragma unroll
                for (int fj = 0; fj < 8; fj++) {
                    bf16x8 b = *(const bf16x8*)&Bs[fj * 16 + lr][ki * 32 + lg * 8];
                    acc[fj] = __builtin_amdgcn_mfma_f32_16x16x32_bf16(a[ks], b, acc[fj], 0, 0, 0);
                }
            }
        }
#pragma unroll
        for (int fj = 0; fj < 8; fj++) {
            int col = c0 + fj * 16 + lr;
            if (col < N_ENT) {
#pragma unroll
                for (int r = 0; r < 4; r++) topk_insert(tv[r], ti[r], acc[fj][r], col);
            }
        }
    }
#pragma unroll
    for (int r = 0; r < 4; r++) {
        int gr = rbase + 4 * lg + r;
        int used = 0;
#pragma unroll
        for (int s = 0; s < 6; s++) {
            float hv = sel6f(tv[r], used);
            int hi = sel6i(ti[r], used);
            float bv = hv; int bi = hi;
#pragma unroll
            for (int m = 1; m < 16; m <<= 1) {
                float ov = __shfl_xor(bv, m);
                int oi = __shfl_xor(bi, m);
                if (better(ov, oi, bv, bi)) { bv = ov; bi = oi; }
            }
            if (hi == bi) used++;  // col indices unique across lanes
            if (lr == 0 && gr < N_ENT) {
                tval[((size_t)cs * N_ENT + gr) * 6 + s] = bv;
                tidx[((size_t)cs * N_ENT + gr) * 6 + s] = bi;
            }
        }
    }
}

__global__ __launch_bounds__(64) void p2_combine(const float* __restrict__ tval,
                                                 const int* __restrict__ tidx,
                                                 const float* __restrict__ denom,
                                                 const ushort* __restrict__ snb,
                                                 const float* __restrict__ mn,
                                                 float* __restrict__ lsum) {
    const int n = blockIdx.x;
    __shared__ float sv[CS2 * 6];
    __shared__ int sidx[CS2 * 6];
    __shared__ int sel[6];
    int t = threadIdx.x;
    for (int u = t; u < CS2 * 6; u += 64) {
        int cs = u / 6, s = u % 6;
        sv[u] = tval[((size_t)cs * N_ENT + n) * 6 + s];
        sidx[u] = tidx[((size_t)cs * N_ENT + n) * 6 + s];
    }
    __syncthreads();
    if (t == 0) {
        float pv = 1e30f; int pi = -1;
        for (int s = 0; s < 6; s++) {
            float bv = -1e30f; int bi = 0x7fffffff;
            for (int u = 0; u < CS2 * 6; u++) {
                float v = sv[u]; int i = sidx[u];
                if (better(pv, pi, v, i) && better(v, i, bv, bi)) { bv = v; bi = i; }
            }
            sel[s] = bi;
            pv = bv; pi = bi;
        }
    }
    __syncthreads();
    float pos = 0.f;
    for (int s = 0; s < 6; s++) {
        const float* mr = mn + (size_t)sel[s] * 256;
        float d = 0.f;
        for (int dd = t; dd < 256; dd += 64)
            d += bf2f(snb[(size_t)n * 256 + dd]) * mr[dd];
        for (int off = 32; off; off >>= 1) d += __shfl_down(d, off);
        if (t == 0) pos += __expf(d * INV_TAU);
    }
    if (t == 0) {
        float l = logf(denom[n]) - logf(pos);
        atomicAdd(lsum, l);
    }
}

__global__ void init_lsum(float* lsum) { lsum[0] = 0.f; }

__global__ void finalize_loss(const float* __restrict__ lsum, float* __restrict__ out) {
    out[12800000] = lsum[0] * (1.f / (N_ENT * 5.0f));
}

extern "C" void kernel_launch(void* const* d_in, const int* in_sizes, int n_in,
                              void* d_out, int out_size, void* d_ws, size_t ws_size,
                              hipStream_t stream) {
    (void)in_sizes; (void)n_in; (void)out_size; (void)ws_size;
    const float* st = (const float*)d_in[0];     // [10000][256][5]
    const float* mm = (const float*)d_in[1];     // [10000][768]
    const float* W1 = (const float*)d_in[2];     // [5][256][768]
    const float* b1 = (const float*)d_in[3];     // [5][256]
    const float* W2 = (const float*)d_in[4];     // [5][256][256]
    const float* b2 = (const float*)d_in[5];     // [5][256]
    const float* gamma = (const float*)d_in[6];  // [5][256]
    const float* beta = (const float*)d_in[7];   // [5][256]
    float* out = (float*)d_out;                  // 12.8M mm_out + 1 loss

    float* bufH = (float*)d_ws;                    // [5][10000][256] gelu(h1) fp32
    float* bufE = bufH + 12800000ull;              // [5][10000][256] mm_enc (BN'd in place)
    float* fp = bufE + 12800000ull;
    // split-bf16 weights
    ushort* w1hi = (ushort*)fp;                    // 983040
    ushort* w1lo = w1hi + 983040;
    ushort* w2hi = w1lo + 983040;                  // 327680
    ushort* w2lo = w2hi + 327680;
    fp += (2 * 983040 + 2 * 327680 + 2) / 2;       // 1310720 floats
    float* ps = fp; fp += 5 * 40 * 256;
    float* pss = fp; fp += 5 * 40 * 256;
    float* bn_a = fp; fp += 1280;
    float* bn_b = fp; fp += 1280;
    float* rns = fp; fp += N_ENT;
    float* rnm = fp; fp += N_ENT;
    float* denom = fp; fp += N_ENT;
    float* pmax = fp; fp += CS1 * N_ENT;
    float* psum = fp; fp += CS1 * N_ENT;
    float* tval = fp; fp += CS2 * N_ENT * 6;
    float* lsum = fp; fp += 8;
    int* ip = (int*)fp;
    int* amax = ip; ip += N_ENT;
    int* pidx = ip; ip += CS1 * N_ENT;
    int* tidx = ip; ip += CS2 * N_ENT * 6;
    // loss-stage buffers overlay bufH (free after enc_mfma<false>)
    float* mn = bufH;                              // [10000][256] fp32
    ushort* snb = (ushort*)(bufH + 2560000);       // [NPAD][256] bf16
    ushort* mnb = snb + (size_t)NPAD * 256;        // [NPAD][256] bf16

    init_lsum<<<1, 1, 0, stream>>>(lsum);
    conv_w<<<3840, 256, 0, stream>>>(W1, w1hi, w1lo, 983040);
    conv_w<<<1280, 256, 0, stream>>>(W2, w2hi, w2lo, 327680);

    enc_mfma<true><<<dim3(79, 2, 5), 256, 0, stream>>>(mm, 0, 768, w1hi, w1lo, b1, bufH);
    enc_mfma<false><<<dim3(79, 2, 5), 256, 0, stream>>>(bufH, (size_t)N_ENT * 256, 256, w2hi, w2lo, b2, bufE);

    bn_part<<<dim3(5, 40), 256, 0, stream>>>(bufE, ps, pss);
    bn_finish<<<5, 256, 0, stream>>>(ps, pss, gamma, beta, bn_a, bn_b);
    bn_apply<<<50000, 256, 0, stream>>>(bufE, bn_a, bn_b, out);

    for (int c = 0; c < 5; c++) {
        rownorm<<<N_ENT, 256, 0, stream>>>(st + c, 1280, 5, rns);
        rownorm<<<N_ENT, 256, 0, stream>>>(bufE + (size_t)c * N_ENT * 256, 256, 1, rnm);
        build_snb<<<NPAD, 256, 0, stream>>>(st, c, rns, snb);
        build_mnb<<<NPAD, 256, 0, stream>>>(bufE, c, rnm, mnb, mn);
        pass1_mfma<<<dim3(NPAD / 128, CS1), 256, 0, stream>>>(snb, mnb, pmax, pidx, psum);
        p1_combine<<<40, 256, 0, stream>>>(pmax, pidx, psum, amax, denom);
        pass2_mfma<<<dim3(NPAD / 64, CS2), 256, 0, stream>>>(mnb, amax, tval, tidx);
        p2_combine<<<N_ENT, 64, 0, stream>>>(tval, tidx, denom, snb, mn, lsum);
    }
    finalize_loss<<<1, 1, 0, stream>>>(lsum, out);
}